// Round 1
// baseline (688.877 us; speedup 1.0000x reference)
//
#include <hip/hip_runtime.h>

#define BATCH 4
#define SEQ   1024
#define HIDN  768
#define NH    12
#define HD    64
#define BHN   48   // BATCH*NH

typedef __attribute__((ext_vector_type(8))) short bf16x8;
typedef __attribute__((ext_vector_type(4))) float f32x4;

#define MFMA(a, b, c) __builtin_amdgcn_mfma_f32_16x16x32_bf16((a), (b), (c), 0, 0, 0)

__device__ inline unsigned short f2bf(float f) {
    union { float f; unsigned u; } v; v.f = f;
    unsigned r = (v.u + 0x7FFFu + ((v.u >> 16) & 1u)) >> 16;
    return (unsigned short)r;
}
__device__ inline float bf2f(unsigned short s) {
    union { unsigned u; float f; } v; v.u = ((unsigned)s) << 16;
    return v.f;
}
__device__ inline unsigned long long pack4(float a, float b, float c, float d) {
    return (unsigned long long)f2bf(a)
         | ((unsigned long long)f2bf(b) << 16)
         | ((unsigned long long)f2bf(c) << 32)
         | ((unsigned long long)f2bf(d) << 48);
}

// ---------------------------------------------------------------------------
// Kernel 1: QKV projection. C[m,n] = sum_k hidden[m,k]*W[n,k] + bias[n]
// out bf16 laid out [bh][l][d], bh = b*12 + h.
// ---------------------------------------------------------------------------
__global__ __launch_bounds__(256) void qkv_kernel(
    const float* __restrict__ hidden,
    const float* __restrict__ Wq, const float* __restrict__ bq,
    const float* __restrict__ Wk, const float* __restrict__ bk,
    const float* __restrict__ Wv, const float* __restrict__ bv,
    unsigned short* __restrict__ Qb, unsigned short* __restrict__ Kb,
    unsigned short* __restrict__ Vb)
{
    const int mt  = blockIdx.x;   // 0..31  (m tile of 128)
    const int nt  = blockIdx.y;   // 0..11  (head; n tile of 64)
    const int mat = blockIdx.z;   // 0:Q 1:K 2:V
    const float* W  = (mat == 0) ? Wq : (mat == 1) ? Wk : Wv;
    const float* bs = (mat == 0) ? bq : (mat == 1) ? bk : bv;
    unsigned short* out = (mat == 0) ? Qb : (mat == 1) ? Kb : Vb;

    const int t = threadIdx.x, lane = t & 63, wid = t >> 6;
    const int row16 = lane & 15, kg = lane >> 4;
    const int m0 = mt * 128;
    const int wm = (wid >> 1) * 64, wn = (wid & 1) * 32;

    __shared__ __align__(16) unsigned short As[128 * 40];
    __shared__ __align__(16) unsigned short Ws[64 * 40];

    f32x4 acc[4][2] = {};

    for (int k0 = 0; k0 < HIDN; k0 += 32) {
        // stage A tile 128x32 fp32 -> bf16
        for (int i = 0; i < 4; ++i) {
            int f4 = t + i * 256;            // 0..1023 float4s
            int r = f4 >> 3, c4 = f4 & 7;
            float4 v = *(const float4*)(hidden + (size_t)(m0 + r) * HIDN + k0 + c4 * 4);
            *(unsigned long long*)&As[r * 40 + c4 * 4] = pack4(v.x, v.y, v.z, v.w);
        }
        // stage W tile 64x32
        for (int i = 0; i < 2; ++i) {
            int f4 = t + i * 256;            // 0..511
            int r = f4 >> 3, c4 = f4 & 7;
            float4 v = *(const float4*)(W + (size_t)(nt * 64 + r) * HIDN + k0 + c4 * 4);
            *(unsigned long long*)&Ws[r * 40 + c4 * 4] = pack4(v.x, v.y, v.z, v.w);
        }
        __syncthreads();
        bf16x8 af[4], bfr[2];
        for (int mf = 0; mf < 4; ++mf)
            af[mf] = *(const bf16x8*)&As[(wm + mf * 16 + row16) * 40 + kg * 8];
        for (int nf = 0; nf < 2; ++nf)
            bfr[nf] = *(const bf16x8*)&Ws[(wn + nf * 16 + row16) * 40 + kg * 8];
        for (int mf = 0; mf < 4; ++mf)
            for (int nf = 0; nf < 2; ++nf)
                acc[mf][nf] = MFMA(af[mf], bfr[nf], acc[mf][nf]);
        __syncthreads();
    }

    const int bh = (m0 / SEQ) * NH + nt;   // m tile never straddles a batch
    for (int nf = 0; nf < 2; ++nf) {
        int d = wn + nf * 16 + row16;
        float bias_v = bs[nt * 64 + d];
        for (int mf = 0; mf < 4; ++mf)
            for (int j = 0; j < 4; ++j) {
                int m = m0 + wm + mf * 16 + kg * 4 + j;
                int l = m & (SEQ - 1);
                out[((size_t)bh * SEQ + l) * HD + d] = f2bf(acc[mf][nf][j] + bias_v);
            }
    }
}

// ---------------------------------------------------------------------------
// Kernel 2: scores[bh][l][r] = ( q.k + (q+k).sm[l,r] ) / 8 + mask[b][r]
// block: 16 l x 32 r tile, ALL 48 bh. 512 threads (8 waves).
// ---------------------------------------------------------------------------
__global__ __launch_bounds__(512) void scores_kernel(
    const float* __restrict__ sm, const float* __restrict__ mask,
    const unsigned short* __restrict__ Qb, const unsigned short* __restrict__ Kb,
    float* __restrict__ S)
{
    const int rt = blockIdx.x, lt = blockIdx.y;
    const int r0 = rt * 32, l0 = lt * 16;
    const int t = threadIdx.x, lane = t & 63, wid = t >> 6;
    const int row16 = lane & 15, kg = lane >> 4;

    __shared__ __align__(16) unsigned short sm_s[16 * 32 * 64];   // 64KB, XOR-swizzled
    __shared__ __align__(16) unsigned short bias_s[16 * 32 * 48]; // 48KB bf16
    __shared__ float mask_s[BATCH * 32];

    // stage sm tile (fp32 -> bf16, swizzle byte bits 4..6 by (l^r)&7)
    for (int i = 0; i < 16; ++i) {
        int f4 = t + i * 512;            // 0..8191 float4s
        int l = f4 >> 9;
        int rem = f4 & 511;
        int r = rem >> 4, d4 = rem & 15;
        float4 v = *(const float4*)(sm + ((size_t)(l0 + l) * SEQ + (r0 + r)) * HD + d4 * 4);
        int idx = (((l * 32 + r) * 64) + d4 * 4) ^ ((((l ^ r) & 7) << 3));
        *(unsigned long long*)&sm_s[idx] = pack4(v.x, v.y, v.z, v.w);
    }
    if (t < BATCH * 32) {
        int b = t >> 5, r = t & 31;
        mask_s[t] = mask[(size_t)b * SEQ + r0 + r];
    }
    __syncthreads();

    // phase 1: bias_q. wave handles l = wid*2 + {0,1}. out[r][bh] per l.
    for (int li = 0; li < 2; ++li) {
        int l = wid * 2 + li;
        bf16x8 af[2][2];
        for (int mf = 0; mf < 2; ++mf)
            for (int kf = 0; kf < 2; ++kf) {
                int r = mf * 16 + row16, d0 = kf * 32 + kg * 8;
                af[mf][kf] = *(const bf16x8*)&sm_s[(((l * 32 + r) * 64) + d0) ^ ((((l ^ r) & 7) << 3))];
            }
        bf16x8 bq8[3][2];
        for (int nf = 0; nf < 3; ++nf)
            for (int kf = 0; kf < 2; ++kf) {
                int bh = nf * 16 + row16, d0 = kf * 32 + kg * 8;
                bq8[nf][kf] = *(const bf16x8*)&Qb[((size_t)bh * SEQ + l0 + l) * HD + d0];
            }
        f32x4 acc[2][3] = {};
        for (int kf = 0; kf < 2; ++kf)
            for (int mf = 0; mf < 2; ++mf)
                for (int nf = 0; nf < 3; ++nf)
                    acc[mf][nf] = MFMA(af[mf][kf], bq8[nf][kf], acc[mf][nf]);
        for (int mf = 0; mf < 2; ++mf)
            for (int nf = 0; nf < 3; ++nf)
                for (int j = 0; j < 4; ++j) {
                    int r = mf * 16 + kg * 4 + j, bh = nf * 16 + row16;
                    bias_s[(l * 32 + r) * 48 + bh] = f2bf(acc[mf][nf][j]);
                }
    }
    __syncthreads();

    // phase 2: bias_k. wave handles r = wid*4 + {0..3}. out[l][bh] per r, += into bias_s.
    for (int ri = 0; ri < 4; ++ri) {
        int r = wid * 4 + ri;
        bf16x8 af[2];
        for (int kf = 0; kf < 2; ++kf) {
            int l = row16, d0 = kf * 32 + kg * 8;
            af[kf] = *(const bf16x8*)&sm_s[(((l * 32 + r) * 64) + d0) ^ ((((l ^ r) & 7) << 3))];
        }
        bf16x8 bk8[3][2];
        for (int nf = 0; nf < 3; ++nf)
            for (int kf = 0; kf < 2; ++kf) {
                int bh = nf * 16 + row16, d0 = kf * 32 + kg * 8;
                bk8[nf][kf] = *(const bf16x8*)&Kb[((size_t)bh * SEQ + r0 + r) * HD + d0];
            }
        f32x4 acc[3] = {};
        for (int kf = 0; kf < 2; ++kf)
            for (int nf = 0; nf < 3; ++nf)
                acc[nf] = MFMA(af[kf], bk8[nf][kf], acc[nf]);
        for (int nf = 0; nf < 3; ++nf)
            for (int j = 0; j < 4; ++j) {
                int l = kg * 4 + j, bh = nf * 16 + row16;
                int idx = (l * 32 + r) * 48 + bh;
                bias_s[idx] = f2bf(bf2f(bias_s[idx]) + acc[nf][j]);
            }
    }
    __syncthreads();

    // phase 3: QK^T + assembly. wave handles bh = wid*6 + {0..5}.
    for (int bi = 0; bi < 6; ++bi) {
        int bh = wid * 6 + bi;
        int b = bh / NH;
        bf16x8 aq[2], bkf[2][2];
        for (int kf = 0; kf < 2; ++kf)
            aq[kf] = *(const bf16x8*)&Qb[((size_t)bh * SEQ + l0 + row16) * HD + kf * 32 + kg * 8];
        for (int nf = 0; nf < 2; ++nf)
            for (int kf = 0; kf < 2; ++kf)
                bkf[nf][kf] = *(const bf16x8*)&Kb[((size_t)bh * SEQ + r0 + nf * 16 + row16) * HD + kf * 32 + kg * 8];
        f32x4 acc[2] = {};
        for (int kf = 0; kf < 2; ++kf)
            for (int nf = 0; nf < 2; ++nf)
                acc[nf] = MFMA(aq[kf], bkf[nf][kf], acc[nf]);
        for (int nf = 0; nf < 2; ++nf) {
            int r = nf * 16 + row16;
            for (int j = 0; j < 4; ++j) {
                int l = kg * 4 + j;
                float s = (acc[nf][j] + bf2f(bias_s[(l * 32 + r) * 48 + bh])) * 0.125f
                        + mask_s[b * 32 + r];
                S[((size_t)bh * SEQ + l0 + l) * SEQ + r0 + r] = s;
            }
        }
    }
}

// ---------------------------------------------------------------------------
// Kernel 3: row softmax. fp32 in, bf16 out written into the row's own slot.
// ---------------------------------------------------------------------------
__global__ __launch_bounds__(256) void softmax_kernel(float* __restrict__ S)
{
    const int row = blockIdx.x;
    float* base = S + (size_t)row * SEQ;
    const int t = threadIdx.x;

    float4 v = ((const float4*)base)[t];
    float m = fmaxf(fmaxf(v.x, v.y), fmaxf(v.z, v.w));
    for (int off = 32; off; off >>= 1) m = fmaxf(m, __shfl_xor(m, off));
    __shared__ float red[4], red2[4];
    if ((t & 63) == 0) red[t >> 6] = m;
    __syncthreads();
    m = fmaxf(fmaxf(red[0], red[1]), fmaxf(red[2], red[3]));

    float e0 = __expf(v.x - m), e1 = __expf(v.y - m);
    float e2 = __expf(v.z - m), e3 = __expf(v.w - m);
    float s = e0 + e1 + e2 + e3;
    for (int off = 32; off; off >>= 1) s += __shfl_xor(s, off);
    if ((t & 63) == 0) red2[t >> 6] = s;
    __syncthreads();
    s = red2[0] + red2[1] + red2[2] + red2[3];
    float inv = 1.0f / s;

    ((unsigned long long*)base)[t] = pack4(e0 * inv, e1 * inv, e2 * inv, e3 * inv);
}

// ---------------------------------------------------------------------------
// Kernel 4: ctx[bh,l,d] = sum_r P[bh,l,r] * V[bh,r,d]; out fp32 [b][l][h*64+d]
// ---------------------------------------------------------------------------
__global__ __launch_bounds__(256) void pv_kernel(
    const float* __restrict__ Sbuf, const unsigned short* __restrict__ Vb,
    float* __restrict__ out)
{
    const int bh = blockIdx.x;
    const int l0 = blockIdx.y * 128;
    const int b = bh / NH, h = bh % NH;
    const int t = threadIdx.x, lane = t & 63, wid = t >> 6;
    const int row16 = lane & 15, kg = lane >> 4;
    const int wm = (wid >> 1) * 64, wn = (wid & 1) * 32;

    __shared__ __align__(16) unsigned short pt[128 * 72];
    __shared__ __align__(16) unsigned short vt[64 * 72];
    const unsigned short* P = (const unsigned short*)Sbuf;   // row stride 2048 bf16

    f32x4 acc[4][2] = {};
    for (int r0 = 0; r0 < SEQ; r0 += 64) {
        for (int i = 0; i < 8; ++i) {
            int f4 = t + i * 256;            // 0..2047 (128*64/4)
            int row = f4 >> 4, c4 = f4 & 15;
            *(unsigned long long*)&pt[row * 72 + c4 * 4] =
                *(const unsigned long long*)&P[((size_t)(bh * SEQ + l0 + row)) * 2048 + r0 + c4 * 4];
        }
        for (int i = 0; i < 4; ++i) {
            int f4 = t + i * 256;            // 0..1023 (64*64/4)
            int r = f4 >> 4, c4 = f4 & 15;
            unsigned long long pk =
                *(const unsigned long long*)&Vb[((size_t)bh * SEQ + r0 + r) * HD + c4 * 4];
            vt[(c4 * 4 + 0) * 72 + r] = (unsigned short)(pk);
            vt[(c4 * 4 + 1) * 72 + r] = (unsigned short)(pk >> 16);
            vt[(c4 * 4 + 2) * 72 + r] = (unsigned short)(pk >> 32);
            vt[(c4 * 4 + 3) * 72 + r] = (unsigned short)(pk >> 48);
        }
        __syncthreads();
        for (int kf = 0; kf < 2; ++kf) {
            int kk = kf * 32 + kg * 8;
            bf16x8 af[4], bfr[2];
            for (int mf = 0; mf < 4; ++mf)
                af[mf] = *(const bf16x8*)&pt[(wm + mf * 16 + row16) * 72 + kk];
            for (int nf = 0; nf < 2; ++nf)
                bfr[nf] = *(const bf16x8*)&vt[(wn + nf * 16 + row16) * 72 + kk];
            for (int mf = 0; mf < 4; ++mf)
                for (int nf = 0; nf < 2; ++nf)
                    acc[mf][nf] = MFMA(af[mf], bfr[nf], acc[mf][nf]);
        }
        __syncthreads();
    }

    for (int nf = 0; nf < 2; ++nf) {
        int d = wn + nf * 16 + row16;
        for (int mf = 0; mf < 4; ++mf)
            for (int j = 0; j < 4; ++j) {
                int l = l0 + wm + mf * 16 + kg * 4 + j;
                out[((size_t)(b * SEQ + l)) * HIDN + h * HD + d] = acc[mf][nf][j];
            }
    }
}

// ---------------------------------------------------------------------------
extern "C" void kernel_launch(void* const* d_in, const int* in_sizes, int n_in,
                              void* d_out, int out_size, void* d_ws, size_t ws_size,
                              hipStream_t stream)
{
    const float* hidden = (const float*)d_in[0];
    const float* mask   = (const float*)d_in[1];
    const float* smat   = (const float*)d_in[2];
    const float* Wq = (const float*)d_in[3];
    const float* bq = (const float*)d_in[4];
    const float* Wk = (const float*)d_in[5];
    const float* bk = (const float*)d_in[6];
    const float* Wv = (const float*)d_in[7];
    const float* bv = (const float*)d_in[8];
    float* out = (float*)d_out;

    char* ws = (char*)d_ws;
    unsigned short* Qb = (unsigned short*)(ws);                 // 6 MB
    unsigned short* Kb = (unsigned short*)(ws + 6291456);       // 6 MB
    unsigned short* Vb = (unsigned short*)(ws + 12582912);      // 6 MB
    float* S = (float*)(ws + 18874368);                         // 192 MB

    qkv_kernel<<<dim3(32, 12, 3), 256, 0, stream>>>(hidden, Wq, bq, Wk, bk, Wv, bv, Qb, Kb, Vb);
    scores_kernel<<<dim3(32, 64), 512, 0, stream>>>(smat, mask, Qb, Kb, S);
    softmax_kernel<<<dim3(BHN * SEQ), 256, 0, stream>>>(S);
    pv_kernel<<<dim3(BHN, 8), 256, 0, stream>>>(S, Vb, out);
}